// Round 1
// baseline (137.776 us; speedup 1.0000x reference)
//
#include <hip/hip_runtime.h>
#include <hip/hip_bf16.h>
#include <stdint.h>
#include <stddef.h>

// DistanceNetwork: sims[n,b] = dot(support[n], input[b]) * rsqrt(||support[n]||^2) * rsqrt(||input||_F^2)
//   support_set: [8192, 1024] fp32   input_image: [2048, 1024] fp32   out: [8192, 2048] fp32
#define M_DIM 8192
#define N_DIM 2048
#define K_DIM 1024

#define BM 128
#define BN 128
#define BK 64
#define NKT (K_DIM / BK)  // 16 K-steps

typedef __attribute__((ext_vector_type(8))) short short8;   // 8 bf16 = 4 VGPRs
typedef __attribute__((ext_vector_type(4))) float float4v;  // MFMA C/D

// fp32 -> bf16 RNE
static __device__ __forceinline__ unsigned short f2bf(float x) {
  union { float f; unsigned u; } c; c.f = x;
  return (unsigned short)((c.u + 0x7FFFu + ((c.u >> 16) & 1u)) >> 16);
}

#define GLOAD_LDS16(g, l)                                           \
  __builtin_amdgcn_global_load_lds(                                 \
      (const __attribute__((address_space(1))) void*)(g),           \
      (__attribute__((address_space(3))) void*)(l), 16, 0, 0)

// ---------------- fused prep ----------------
// One block per 1024-float row. Blocks [0, 8192): support rows -> Sb + smag.
// Blocks [8192, 10240): input rows -> Ib + partials. (GEMM reduces partials
// itself — no serialized finalize dispatch.)
__global__ __launch_bounds__(256) void prep(
    const float* __restrict__ S, const float* __restrict__ I,
    unsigned short* __restrict__ Sb, unsigned short* __restrict__ Ib,
    float* __restrict__ smag, float* __restrict__ partials) {
  const int t = threadIdx.x;
  const int blk = blockIdx.x;
  const bool isS = blk < M_DIM;
  const int row = isS ? blk : blk - M_DIM;
  const float* src = (isS ? S : I) + (size_t)row * K_DIM;
  unsigned short* dst = (isS ? Sb : Ib) + (size_t)row * K_DIM;

  const float4 v = reinterpret_cast<const float4*>(src)[t];
  ushort4 b;
  b.x = f2bf(v.x); b.y = f2bf(v.y); b.z = f2bf(v.z); b.w = f2bf(v.w);
  reinterpret_cast<ushort4*>(dst)[t] = b;

  float ss = v.x * v.x + v.y * v.y + v.z * v.z + v.w * v.w;
#pragma unroll
  for (int m = 32; m >= 1; m >>= 1) ss += __shfl_xor(ss, m, 64);
  __shared__ float wsum[4];
  if ((t & 63) == 0) wsum[t >> 6] = ss;
  __syncthreads();
  if (t == 0) {
    const float tot = wsum[0] + wsum[1] + wsum[2] + wsum[3];
    if (isS) smag[row] = rsqrtf(fmaxf(tot, 1e-10f));
    else     partials[row] = tot;
  }
}

// ---------------- GEMM ----------------
// C[m,n] = smag[m]*imag * sum_k A[m,k]*B[n,k]  (both row-major NT).
// 128x128 tile, BK=64, XOR-swizzled LDS (0 bank conflicts, verified R2).
// R3 change: T3 "minimum 2-phase" double-buffer — issue next tile's
// global_load_lds BEFORE computing current tile; ONE __syncthreads per
// K-step (was 2). The vmcnt drain at the barrier now overlaps ~600+cy of
// ds_read+MFMA instead of being fully exposed (16x per block before).
// Cost: 64 KB LDS -> 2 blocks/CU (was 4); m99/m100 showed that trade is
// >= neutral, and positive when the drain is the exposed critical path.
__global__ __launch_bounds__(256) void gemm_bt(
    const unsigned short* __restrict__ A,  // [M, K] bf16 (support)
    const unsigned short* __restrict__ B,  // [N, K] bf16 (input)
    const float* __restrict__ smag,        // [M]
    const float* __restrict__ partials,    // [2048] input-row sumsq partials
    float* __restrict__ C) {               // [M, N]
  __shared__ unsigned short lA[2][BM * BK];  // 2 x 16 KB
  __shared__ unsigned short lB[2][BN * BK];  // 2 x 16 KB
  __shared__ float wsum[4];

  const int t = threadIdx.x;
  const int lane = t & 63;
  const int wave = t >> 6;
  const int wr = wave >> 1;  // wave row 0..1
  const int wc = wave & 1;   // wave col 0..1

  // XCD-aware swizzle: dispatch heuristic blk%8 -> XCD. Each XCD owns a
  // contiguous 8-bm stripe; bm fastest within a bn phase -> per-phase
  // working set A 2MB + B 256KB < 4MB XCD L2.
  const int blk = blockIdx.x;
  const int xcd = blk & 7;
  const int slot = blk >> 3;
  const int bn = (slot >> 3) * BN;
  const int bm = (xcd * 8 + (slot & 7)) * BM;

  // Staging geometry: tile = 1024 chunks of 16B, XOR-swizzled: chunk
  // (row,kc) lives at position row*8 + (kc ^ (row&7)). LDS dest is
  // wave-uniform base + lane*16 (global_load_lds semantics); the
  // per-lane GLOBAL address carries the inverse swizzle.
  const int rsub = lane >> 3;
  const int kcg = (lane & 7) ^ (rsub & 7);
  const unsigned short* gA[4];
  const unsigned short* gB[4];
  int oSt[4];  // wave-uniform LDS chunk base (in shorts) per 16B-chunk group
#pragma unroll
  for (int i = 0; i < 4; ++i) {
    const int row = i * 32 + wave * 8 + rsub;
    gA[i] = A + (size_t)(bm + row) * K_DIM + kcg * 8;
    gB[i] = B + (size_t)(bn + row) * K_DIM + kcg * 8;
    oSt[i] = (i * 256 + wave * 64) * 8;
  }

  // Prologue: stage K-tile 0 into buffer 0 (issued before the partials
  // reduce so the VMEM queue leads with the tile loads).
#pragma unroll
  for (int i = 0; i < 4; ++i) GLOAD_LDS16(gA[i], &lA[0][oSt[i]]);
#pragma unroll
  for (int i = 0; i < 4; ++i) GLOAD_LDS16(gB[i], &lB[0][oSt[i]]);
#pragma unroll
  for (int i = 0; i < 4; ++i) { gA[i] += BK; gB[i] += BK; }

  // Reduce input sum-of-squares (8 loads/thread), result parked in wsum;
  // the prologue __syncthreads makes it visible. Overlaps with staging.
  {
    float p = 0.f;
#pragma unroll
    for (int i = 0; i < 2048 / 256; ++i) p += partials[t + i * 256];
#pragma unroll
    for (int m = 32; m >= 1; m >>= 1) p += __shfl_xor(p, m, 64);
    if ((t & 63) == 0) wsum[t >> 6] = p;
  }

  // Fragment read bases: A[m = lane&15][k = (lane>>4)*8 + j]
  const int fr = lane & 15;
  const int q = lane >> 4;
  const int rOffA = (wr * 64 + fr) * BK;
  const int rOffB = (wc * 64 + fr) * BK;
  const int sw = fr & 7;  // read-side swizzle term

  float4v acc[4][4];
#pragma unroll
  for (int i = 0; i < 4; ++i)
#pragma unroll
    for (int j = 0; j < 4; ++j) acc[i][j] = (float4v)0.0f;

  __syncthreads();  // drains prologue stage; publishes wsum

#pragma unroll 2
  for (int kt = 0; kt < NKT; ++kt) {
    const int cur = kt & 1;
    // Phase 1: issue NEXT tile's stage into the other buffer (overlaps
    // with this tile's ds_read+MFMA below; drained by the barrier).
    if (kt + 1 < NKT) {
      const int nxt = cur ^ 1;
#pragma unroll
      for (int i = 0; i < 4; ++i) GLOAD_LDS16(gA[i], &lA[nxt][oSt[i]]);
#pragma unroll
      for (int i = 0; i < 4; ++i) GLOAD_LDS16(gB[i], &lB[nxt][oSt[i]]);
#pragma unroll
      for (int i = 0; i < 4; ++i) { gA[i] += BK; gB[i] += BK; }
    }

    // Phase 2: compute current tile from buffer `cur`.
    const unsigned short* rA = &lA[cur][0] + rOffA;
    const unsigned short* rB = &lB[cur][0] + rOffB;
#pragma unroll
    for (int s = 0; s < 2; ++s) {  // two MFMA k-steps per staged slab
      const int pc = ((4 * s + q) ^ sw) * 8;
      short8 af[4], bfr[4];
#pragma unroll
      for (int i = 0; i < 4; ++i)
        af[i] = *reinterpret_cast<const short8*>(rA + i * 16 * BK + pc);
#pragma unroll
      for (int j = 0; j < 4; ++j)
        bfr[j] = *reinterpret_cast<const short8*>(rB + j * 16 * BK + pc);
#pragma unroll
      for (int i = 0; i < 4; ++i)
#pragma unroll
        for (int j = 0; j < 4; ++j)
          acc[i][j] = __builtin_amdgcn_mfma_f32_16x16x32_bf16(af[i], bfr[j], acc[i][j], 0, 0, 0);
    }

    // ONE barrier per K-step: waits own stage (vmcnt) + everyone's reads
    // of buffer `cur` done, so next iter may overwrite it.
    __syncthreads();
  }

  // Epilogue: C/D layout col = lane&15, row = (lane>>4)*4 + reg
  const float imag = rsqrtf(fmaxf(wsum[0] + wsum[1] + wsum[2] + wsum[3], 1e-10f));
#pragma unroll
  for (int i = 0; i < 4; ++i) {
    const int rbase = bm + wr * 64 + i * 16 + q * 4;
#pragma unroll
    for (int r = 0; r < 4; ++r) {
      const int row = rbase + r;
      const float s = smag[row] * imag;
      float* crow = C + (size_t)row * N_DIM + bn + wc * 64 + fr;
#pragma unroll
      for (int j = 0; j < 4; ++j) crow[j * 16] = acc[i][j][r] * s;
    }
  }
}

// ---------------- launch ----------------
extern "C" void kernel_launch(void* const* d_in, const int* in_sizes, int n_in,
                              void* d_out, int out_size, void* d_ws, size_t ws_size,
                              hipStream_t stream) {
  const float* S = (const float*)d_in[0];  // support_set [8192,1024]
  const float* I = (const float*)d_in[1];  // input_image [2048,1024]
  float* out = (float*)d_out;

  // ws layout: Sb bf16 16MB | Ib bf16 4MB | smag 32KB | partials 8KB
  unsigned char* ws = (unsigned char*)d_ws;
  unsigned short* Sb = (unsigned short*)ws;
  unsigned short* Ib = (unsigned short*)(ws + (size_t)M_DIM * K_DIM * 2);
  float* smag = (float*)(ws + (size_t)M_DIM * K_DIM * 2 + (size_t)N_DIM * K_DIM * 2);
  float* partials = smag + M_DIM;

  hipLaunchKernelGGL(prep, dim3(M_DIM + N_DIM), dim3(256), 0, stream,
                     S, I, Sb, Ib, smag, partials);
  hipLaunchKernelGGL(gemm_bt, dim3((M_DIM / BM) * (N_DIM / BN)), dim3(256), 0, stream,
                     Sb, Ib, smag, partials, out);
}

// Round 2
// 127.871 us; speedup vs baseline: 1.0775x; 1.0775x over previous
//
#include <hip/hip_runtime.h>
#include <hip/hip_bf16.h>
#include <stdint.h>
#include <stddef.h>

// DistanceNetwork: sims[n,b] = dot(support[n], input[b]) * rsqrt(||support[n]||^2) * rsqrt(||input||_F^2)
//   support_set: [8192, 1024] fp32   input_image: [2048, 1024] fp32   out: [8192, 2048] fp32
#define M_DIM 8192
#define N_DIM 2048
#define K_DIM 1024

// R2: 256x256 8-phase counted-vmcnt schedule (T3+T4+T5). 512 thr, 128KB LDS.
#define BM 256
#define BN 256
#define BK 64
#define NKT (K_DIM / BK)  // 16 K-tiles
#define NITER (NKT / 2)   // 8 iterations, 2 K-tiles each

typedef __attribute__((ext_vector_type(8))) short short8;   // 8 bf16 = 4 VGPRs
typedef __attribute__((ext_vector_type(4))) float float4v;  // MFMA C/D

// fp32 -> bf16 RNE
static __device__ __forceinline__ unsigned short f2bf(float x) {
  union { float f; unsigned u; } c; c.f = x;
  return (unsigned short)((c.u + 0x7FFFu + ((c.u >> 16) & 1u)) >> 16);
}

#define GLOAD_LDS16(g, l)                                           \
  __builtin_amdgcn_global_load_lds(                                 \
      (const __attribute__((address_space(1))) void*)(g),           \
      (__attribute__((address_space(3))) void*)(l), 16, 0, 0)

// ---------------- fused prep ----------------
// One block per 1024-float row. Blocks [0, 8192): support rows -> Sb + smag.
// Blocks [8192, 10240): input rows -> Ib + partials.
__global__ __launch_bounds__(256) void prep(
    const float* __restrict__ S, const float* __restrict__ I,
    unsigned short* __restrict__ Sb, unsigned short* __restrict__ Ib,
    float* __restrict__ smag, float* __restrict__ partials) {
  const int t = threadIdx.x;
  const int blk = blockIdx.x;
  const bool isS = blk < M_DIM;
  const int row = isS ? blk : blk - M_DIM;
  const float* src = (isS ? S : I) + (size_t)row * K_DIM;
  unsigned short* dst = (isS ? Sb : Ib) + (size_t)row * K_DIM;

  const float4 v = reinterpret_cast<const float4*>(src)[t];
  ushort4 b;
  b.x = f2bf(v.x); b.y = f2bf(v.y); b.z = f2bf(v.z); b.w = f2bf(v.w);
  reinterpret_cast<ushort4*>(dst)[t] = b;

  float ss = v.x * v.x + v.y * v.y + v.z * v.z + v.w * v.w;
#pragma unroll
  for (int m = 32; m >= 1; m >>= 1) ss += __shfl_xor(ss, m, 64);
  __shared__ float wsum[4];
  if ((t & 63) == 0) wsum[t >> 6] = ss;
  __syncthreads();
  if (t == 0) {
    const float tot = wsum[0] + wsum[1] + wsum[2] + wsum[3];
    if (isS) smag[row] = rsqrtf(fmaxf(tot, 1e-10f));
    else     partials[row] = tot;
  }
}

// ---------------- GEMM: 256^2 8-phase counted-vmcnt ----------------
// Per iteration: process K-tiles (2i)->buf0 [phases 1-4], (2i+1)->buf1 [5-8].
// Every phase: {ds_read frag subtile | stage 2 global_load_lds | barrier |
// lgkmcnt(0) | setprio(1) 16xMFMA setprio(0) | barrier}. vmcnt(6) ONLY at
// phases 4 and 8 (3 load-pairs stay in flight across barriers — T4).
// Stage schedule (verified region-safety: each region staged >=1 barrier
// after its last reader; drained by a vmcnt >=1 barrier before first read):
//   ph1: T_{i,b}.A1A3   ph2: T_{i+1,a}.B01  ph3: T_{i+1,a}.B23
//   ph4: T_{i+1,a}.A0A2 ph5: T_{i+1,a}.A1A3 ph6: T_{i+1,b}.B01
//   ph7: T_{i+1,b}.B23  ph8: T_{i+1,b}.A0A2
// LDS: [buf][half][128 rows][8 chunks of 16B], chunk (r,kc) at r*8+(kc^(r&7))
// — same swizzle as R1 (0 bank conflicts measured). global_load_lds writes
// linearly; per-lane GLOBAL address carries the inverse swizzle.
__global__ __launch_bounds__(512, 2) void gemm_bt(
    const unsigned short* __restrict__ A,  // [M, K] bf16 (support)
    const unsigned short* __restrict__ B,  // [N, K] bf16 (input)
    const float* __restrict__ smag,        // [M]
    const float* __restrict__ partials,    // [2048] input-row sumsq partials
    float* __restrict__ C) {               // [M, N]
  __shared__ __align__(16) unsigned short lA[32768];  // 2 buf x 2 half x 8192
  __shared__ __align__(16) unsigned short lB[32768];
  __shared__ float wsum[8];

  const int t = threadIdx.x;     // 0..511
  const int lane = t & 63;
  const int wave = t >> 6;       // 0..7
  const int wr = wave >> 2;      // 0..1  (M half)
  const int wc = wave & 3;       // 0..3  (N quarter)

  // XCD swizzle: 256 blocks, 1/CU. Each XCD: 4 contiguous bm-tiles x 8 bn.
  const int blk = blockIdx.x;
  const int xcd = blk & 7;
  const int slot = blk >> 3;     // 0..31
  const int bm = (xcd * 4 + (slot & 3)) * BM;
  const int bn = (slot >> 2) * BN;

  // Input Frobenius-norm partials reduce (before staging so its vmem
  // consumption doesn't perturb the staging vmcnt accounting).
  {
    float p = partials[t] + partials[t + 512] + partials[t + 1024] + partials[t + 1536];
#pragma unroll
    for (int m = 32; m >= 1; m >>= 1) p += __shfl_xor(p, m, 64);
    if (lane == 0) wsum[wave] = p;
  }

  // Staging: each gload covers 64 rows (512 lanes x 16B). Thread t stages
  // chunk t: row-in-load = t>>3, stored pos t&7 holds logical kc = (t&7)^(row&7).
  const int srow = t >> 3;
  const int skc = (t & 7) ^ (srow & 7);
  const unsigned short* gA[4];   // loads j: tile rows [64j, 64j+64)
  const unsigned short* gB[4];
  int aoff[4];                   // LDS wave-uniform dest (shorts), per load j
#pragma unroll
  for (int j = 0; j < 4; ++j) {
    gA[j] = A + (size_t)(bm + j * 64 + srow) * K_DIM + skc * 8;
    gB[j] = B + (size_t)(bn + j * 64 + srow) * K_DIM + skc * 8;
    aoff[j] = (j >> 1) * 8192 + (j & 1) * 4096 + wave * 512;
  }

#define STAGE_A(j, buf) do { GLOAD_LDS16(gA[j], &lA[(buf) * 16384 + aoff[j]]); gA[j] += BK; } while (0)
#define STAGE_B(j, buf) do { GLOAD_LDS16(gB[j], &lB[(buf) * 16384 + aoff[j]]); gB[j] += BK; } while (0)
#define SP1(buf) do { STAGE_B(0, buf); STAGE_B(1, buf); } while (0)  // B rows 0-127
#define SP2(buf) do { STAGE_B(2, buf); STAGE_B(3, buf); } while (0)  // B rows 128-255
#define SP3(buf) do { STAGE_A(0, buf); STAGE_A(2, buf); } while (0)  // A rows 0-63 per half
#define SP4(buf) do { STAGE_A(1, buf); STAGE_A(3, buf); } while (0)  // A rows 64-127 per half

  // Fragment read bases (same swizzled layout as R1, verified 0 conflicts).
  const int fr = lane & 15;
  const int q = lane >> 4;
  const int pc0 = (q ^ (fr & 7)) * 8;        // k-step s=0 chunk offset (shorts)
  const int pc1 = ((4 + q) ^ (fr & 7)) * 8;  // k-step s=1
  const unsigned short* rA = lA + wr * 8192 + fr * 64;
  const unsigned short* rB = lB + (wc >> 1) * 8192 + ((wc & 1) * 64 + fr) * 64;

  short8 af[2][2];   // A frags: [m2][s] for current phase's mi pair
  short8 bf[4][2];   // B frags: [nj][s], held across a K-tile's 4 phases
  float4v acc[8][4];
#pragma unroll
  for (int i = 0; i < 8; ++i)
#pragma unroll
    for (int j = 0; j < 4; ++j) acc[i][j] = (float4v)0.0f;

#define BARRIER() __builtin_amdgcn_s_barrier()
#define LGKM0() asm volatile("s_waitcnt lgkmcnt(0)" ::: "memory")
#define VM6() asm volatile("s_waitcnt vmcnt(6)" ::: "memory")
#define VM0() asm volatile("s_waitcnt vmcnt(0)" ::: "memory")
#define PRIO1() __builtin_amdgcn_s_setprio(1)
#define PRIO0() __builtin_amdgcn_s_setprio(0)

#define LOADB(buf) do {                                                        \
    _Pragma("unroll") for (int nj = 0; nj < 4; ++nj) {                         \
      bf[nj][0] = *reinterpret_cast<const short8*>(rB + (buf) * 16384 + nj * 1024 + pc0); \
      bf[nj][1] = *reinterpret_cast<const short8*>(rB + (buf) * 16384 + nj * 1024 + pc1); \
    } } while (0)

#define LOADA(pi, buf) do {                                                    \
    _Pragma("unroll") for (int m2 = 0; m2 < 2; ++m2) {                         \
      af[m2][0] = *reinterpret_cast<const short8*>(rA + (buf) * 16384 + ((pi) * 2 + m2) * 1024 + pc0); \
      af[m2][1] = *reinterpret_cast<const short8*>(rA + (buf) * 16384 + ((pi) * 2 + m2) * 1024 + pc1); \
    } } while (0)

#define MFMA16(pi) do {                                                        \
    _Pragma("unroll") for (int m2 = 0; m2 < 2; ++m2)                           \
    _Pragma("unroll") for (int nj = 0; nj < 4; ++nj) {                         \
      acc[(pi) * 2 + m2][nj] = __builtin_amdgcn_mfma_f32_16x16x32_bf16(        \
          af[m2][0], bf[nj][0], acc[(pi) * 2 + m2][nj], 0, 0, 0);              \
      acc[(pi) * 2 + m2][nj] = __builtin_amdgcn_mfma_f32_16x16x32_bf16(        \
          af[m2][1], bf[nj][1], acc[(pi) * 2 + m2][nj], 0, 0, 0);              \
    } } while (0)

#define ITER(DS) do {                                                          \
    /* phase 1 (buf0, mi 0-1) */                                               \
    LOADB(0); LOADA(0, 0); SP4(1);                                             \
    BARRIER(); LGKM0(); PRIO1(); MFMA16(0); PRIO0(); BARRIER();                \
    /* phase 2 (mi 2-3) */                                                     \
    LOADA(1, 0); if (DS) SP1(0);                                               \
    BARRIER(); LGKM0(); PRIO1(); MFMA16(1); PRIO0(); BARRIER();                \
    /* phase 3 (mi 4-5) */                                                     \
    LOADA(2, 0); if (DS) SP2(0);                                               \
    BARRIER(); LGKM0(); PRIO1(); MFMA16(2); PRIO0(); BARRIER();                \
    /* phase 4 (mi 6-7) + counted vmcnt */                                     \
    LOADA(3, 0); if (DS) SP3(0);                                               \
    if (DS) { VM6(); } else { VM0(); }                                         \
    BARRIER(); LGKM0(); PRIO1(); MFMA16(3); PRIO0(); BARRIER();                \
    /* phase 5 (buf1, mi 0-1) */                                               \
    LOADB(1); LOADA(0, 1); if (DS) SP4(0);                                     \
    BARRIER(); LGKM0(); PRIO1(); MFMA16(0); PRIO0(); BARRIER();                \
    /* phase 6 (mi 2-3) */                                                     \
    LOADA(1, 1); if (DS) SP1(1);                                               \
    BARRIER(); LGKM0(); PRIO1(); MFMA16(1); PRIO0(); BARRIER();                \
    /* phase 7 (mi 4-5) */                                                     \
    LOADA(2, 1); if (DS) SP2(1);                                               \
    BARRIER(); LGKM0(); PRIO1(); MFMA16(2); PRIO0(); BARRIER();                \
    /* phase 8 (mi 6-7) + counted vmcnt */                                     \
    LOADA(3, 1); if (DS) SP3(1);                                               \
    if (DS) { VM6(); }                                                         \
    BARRIER(); LGKM0(); PRIO1(); MFMA16(3); PRIO0(); BARRIER();                \
  } while (0)

  // Prologue: T0 fully (4 pairs) + T1.{B01,B23,A0A2} (3 pairs) = 14 loads.
  // vmcnt(6) drains the 8 oldest = all of T0.
  SP1(0); SP2(0); SP3(0); SP4(0);
  SP1(1); SP2(1); SP3(1);
  VM6();
  BARRIER();  // also publishes wsum

#pragma unroll 1
  for (int it = 0; it < NITER - 1; ++it) ITER(1);
  ITER(0);  // epilogue iteration: ph1 stages T15.A1A3, ph4 drains vmcnt(0)

  // Epilogue: C/D layout col = lane&15, row = (lane>>4)*4 + reg
  const float imag = rsqrtf(fmaxf(wsum[0] + wsum[1] + wsum[2] + wsum[3] +
                                  wsum[4] + wsum[5] + wsum[6] + wsum[7], 1e-10f));
#pragma unroll
  for (int mi = 0; mi < 8; ++mi) {
    const int rbase = bm + wr * 128 + mi * 16 + q * 4;
#pragma unroll
    for (int r = 0; r < 4; ++r) {
      const int row = rbase + r;
      const float sc = smag[row] * imag;
      float* crow = C + (size_t)row * N_DIM + bn + wc * 64 + fr;
#pragma unroll
      for (int nj = 0; nj < 4; ++nj) crow[nj * 16] = acc[mi][nj][r] * sc;
    }
  }
}

// ---------------- launch ----------------
extern "C" void kernel_launch(void* const* d_in, const int* in_sizes, int n_in,
                              void* d_out, int out_size, void* d_ws, size_t ws_size,
                              hipStream_t stream) {
  const float* S = (const float*)d_in[0];  // support_set [8192,1024]
  const float* I = (const float*)d_in[1];  // input_image [2048,1024]
  float* out = (float*)d_out;

  // ws layout: Sb bf16 16MB | Ib bf16 4MB | smag 32KB | partials 8KB
  unsigned char* ws = (unsigned char*)d_ws;
  unsigned short* Sb = (unsigned short*)ws;
  unsigned short* Ib = (unsigned short*)(ws + (size_t)M_DIM * K_DIM * 2);
  float* smag = (float*)(ws + (size_t)M_DIM * K_DIM * 2 + (size_t)N_DIM * K_DIM * 2);
  float* partials = smag + M_DIM;

  hipLaunchKernelGGL(prep, dim3(M_DIM + N_DIM), dim3(256), 0, stream,
                     S, I, Sb, Ib, smag, partials);
  hipLaunchKernelGGL(gemm_bt, dim3((M_DIM / BM) * (N_DIM / BN)), dim3(512), 0, stream,
                     Sb, Ib, smag, partials, out);
}

// Round 3
// 126.943 us; speedup vs baseline: 1.0853x; 1.0073x over previous
//
#include <hip/hip_runtime.h>
#include <hip/hip_bf16.h>
#include <stdint.h>
#include <stddef.h>

// DistanceNetwork: sims[n,b] = dot(support[n], input[b]) * rsqrt(||support[n]||^2) * rsqrt(||input||_F^2)
//   support_set: [8192, 1024] fp32   input_image: [2048, 1024] fp32   out: [8192, 2048] fp32
#define M_DIM 8192
#define N_DIM 2048
#define K_DIM 1024

// R3: 256x256, 8-phase, register-fragment PREFETCH pipeline (reads for phase
// p+1 issue in phase p's body; MFMA consumes bank loaded in phase p-1).
// One barrier/phase; counted vmcnt (never 0 in steady loop).
#define BM 256
#define BN 256
#define BK 64
#define NKT (K_DIM / BK)  // 16 K-tiles
#define NITER (NKT / 2)   // 8 iterations (7 full + 1 tail)

typedef __attribute__((ext_vector_type(8))) short short8;   // 8 bf16 = 4 VGPRs
typedef __attribute__((ext_vector_type(4))) float float4v;  // MFMA C/D

// fp32 -> bf16 RNE
static __device__ __forceinline__ unsigned short f2bf(float x) {
  union { float f; unsigned u; } c; c.f = x;
  return (unsigned short)((c.u + 0x7FFFu + ((c.u >> 16) & 1u)) >> 16);
}

#define GLOAD_LDS16(g, l)                                           \
  __builtin_amdgcn_global_load_lds(                                 \
      (const __attribute__((address_space(1))) void*)(g),           \
      (__attribute__((address_space(3))) void*)(l), 16, 0, 0)

// ---------------- fused prep ----------------
// R3: wave-per-row (no __syncthreads, no LDS). 2560 blocks x 256 thr (4 waves).
// Blocks [0,2048): support rows 4*blk+wave -> Sb + smag.
// Blocks [2048,2560): input rows -> Ib + partials.
__global__ __launch_bounds__(256) void prep(
    const float* __restrict__ S, const float* __restrict__ I,
    unsigned short* __restrict__ Sb, unsigned short* __restrict__ Ib,
    float* __restrict__ smag, float* __restrict__ partials) {
  const int t = threadIdx.x;
  const int lane = t & 63;
  const int wave = t >> 6;
  const int blk = blockIdx.x;
  const bool isS = blk < 2048;
  const int row = (isS ? blk : blk - 2048) * 4 + wave;
  const float* src = (isS ? S : I) + (size_t)row * K_DIM;
  unsigned short* dst = (isS ? Sb : Ib) + (size_t)row * K_DIM;

  float ss = 0.f;
#pragma unroll
  for (int i = 0; i < 4; ++i) {
    const float4 v = reinterpret_cast<const float4*>(src)[lane + i * 64];
    ushort4 b;
    b.x = f2bf(v.x); b.y = f2bf(v.y); b.z = f2bf(v.z); b.w = f2bf(v.w);
    reinterpret_cast<ushort4*>(dst)[lane + i * 64] = b;
    ss += v.x * v.x + v.y * v.y + v.z * v.z + v.w * v.w;
  }
#pragma unroll
  for (int m = 32; m >= 1; m >>= 1) ss += __shfl_xor(ss, m, 64);
  if (lane == 0) {
    if (isS) smag[row] = rsqrtf(fmaxf(ss, 1e-10f));
    else     partials[row] = ss;
  }
}

// ---------------- GEMM: 256^2 prefetch-pipelined 8-phase ----------------
// Phase p: [stage SP][counted VMW][BARRIER][prefetch ds_reads for p+1]
//          [setprio1; 16 MFMA on bank loaded at p-1; setprio0]
// Banks: odd phases consume af0, even consume af1; bfA for K-tile a (ph1-4),
// bfB for K-tile b (ph5-8). All indices compile-time (rule #20).
// vmcnt ledger (steady, 2 loads/SP, verified cycle-closure at 8 in flight):
//   ph2: VMW(10) drains S4(buf0 cur)   [issued 5 phases back]
//   ph4: VMW(8)  drains S1,S2,S3(buf1) [first buf1 read is ph4-body]
//   ph6: VMW(10) drains S4(buf1)
//   ph8: VMW(8)  drains S1,S2,S3(buf0 next)
// Write-after-read: each staged region's last reader completed >=1 barrier
// earlier (reads for phase p complete before phase p's MFMA via compiler's
// counted lgkmcnt; stages issue >=2 phases after last read issue).
__global__ __launch_bounds__(512, 2) void gemm_bt(
    const unsigned short* __restrict__ A,  // [M, K] bf16 (support)
    const unsigned short* __restrict__ B,  // [N, K] bf16 (input)
    const float* __restrict__ smag,        // [M]
    const float* __restrict__ partials,    // [2048] input-row sumsq partials
    float* __restrict__ C) {               // [M, N]
  __shared__ __align__(16) unsigned short lA[32768];  // 2 buf x 2 half x 8192
  __shared__ __align__(16) unsigned short lB[32768];
  __shared__ float wsum[8];

  const int t = threadIdx.x;     // 0..511
  const int lane = t & 63;
  const int wave = t >> 6;       // 0..7
  const int wr = wave >> 2;      // 0..1  (M half)
  const int wc = wave & 3;       // 0..3  (N quarter)

  // XCD swizzle: 256 blocks, 1/CU. Each XCD: 4 contiguous bm-tiles x 8 bn.
  const int blk = blockIdx.x;
  const int xcd = blk & 7;
  const int slot = blk >> 3;     // 0..31
  const int bm = (xcd * 4 + (slot & 3)) * BM;
  const int bn = (slot >> 2) * BN;

  // Input Frobenius-norm partials reduce. VMW(0) after keeps the vmcnt queue
  // pure-stages for the ledger below.
  {
    float p = partials[t] + partials[t + 512] + partials[t + 1024] + partials[t + 1536];
#pragma unroll
    for (int m = 32; m >= 1; m >>= 1) p += __shfl_xor(p, m, 64);
    if (lane == 0) wsum[wave] = p;
  }
  asm volatile("s_waitcnt vmcnt(0)" ::: "memory");

  // Staging: thread t covers row-in-load = t>>3; stored chunk t&7 holds
  // logical kc = (t&7)^(row&7)  (XOR swizzle via pre-swizzled global src).
  const int srow = t >> 3;
  const int skc = (t & 7) ^ (srow & 7);
  const unsigned short* gA[4];   // loads j: tile rows [64j, 64j+64)
  const unsigned short* gB[4];
  int aoff[4];                   // LDS wave-uniform dest (shorts), per load j
#pragma unroll
  for (int j = 0; j < 4; ++j) {
    gA[j] = A + (size_t)(bm + j * 64 + srow) * K_DIM + skc * 8;
    gB[j] = B + (size_t)(bn + j * 64 + srow) * K_DIM + skc * 8;
    aoff[j] = (j >> 1) * 8192 + (j & 1) * 4096 + wave * 512;
  }

#define STAGE_A(j, buf) do { GLOAD_LDS16(gA[j], &lA[(buf) * 16384 + aoff[j]]); gA[j] += BK; } while (0)
#define STAGE_B(j, buf) do { GLOAD_LDS16(gB[j], &lB[(buf) * 16384 + aoff[j]]); gB[j] += BK; } while (0)
#define SP1(buf) do { STAGE_B(0, buf); STAGE_B(1, buf); } while (0)  // B rows 0-127
#define SP2(buf) do { STAGE_B(2, buf); STAGE_B(3, buf); } while (0)  // B rows 128-255
#define SP3(buf) do { STAGE_A(0, buf); STAGE_A(2, buf); } while (0)  // A mi 0-3 (both halves)
#define SP4(buf) do { STAGE_A(1, buf); STAGE_A(3, buf); } while (0)  // A mi 4-7 (both halves)

  // Fragment read bases (swizzled layout, 0 conflicts verified R1/R2).
  const int fr = lane & 15;
  const int q = lane >> 4;
  const int pc0 = (q ^ (fr & 7)) * 8;        // k-step s=0 chunk offset (shorts)
  const int pc1 = ((4 + q) ^ (fr & 7)) * 8;  // k-step s=1
  const unsigned short* rA = lA + wr * 8192 + fr * 64;
  const unsigned short* rB = lB + (wc >> 1) * 8192 + ((wc & 1) * 64 + fr) * 64;

  short8 af0[2][2], af1[2][2];   // A frag banks: [m2][s]; odd phases use af0
  short8 bfA[4][2], bfB[4][2];   // B frags per K-tile: [nj][s]
  float4v acc[8][4];
#pragma unroll
  for (int i = 0; i < 8; ++i)
#pragma unroll
    for (int j = 0; j < 4; ++j) acc[i][j] = (float4v)0.0f;

#define BARRIER() __builtin_amdgcn_s_barrier()
#define VMW(n) asm volatile("s_waitcnt vmcnt(" #n ")" ::: "memory")
#define PRIO1() __builtin_amdgcn_s_setprio(1)
#define PRIO0() __builtin_amdgcn_s_setprio(0)

#define LOADB(bank, buf) do {                                                  \
    _Pragma("unroll") for (int nj = 0; nj < 4; ++nj) {                         \
      bank[nj][0] = *reinterpret_cast<const short8*>(rB + (buf) * 16384 + nj * 1024 + pc0); \
      bank[nj][1] = *reinterpret_cast<const short8*>(rB + (buf) * 16384 + nj * 1024 + pc1); \
    } } while (0)

#define LOADA(bank, buf, pi) do {                                              \
    _Pragma("unroll") for (int m2 = 0; m2 < 2; ++m2) {                         \
      bank[m2][0] = *reinterpret_cast<const short8*>(rA + (buf) * 16384 + ((pi) * 2 + m2) * 1024 + pc0); \
      bank[m2][1] = *reinterpret_cast<const short8*>(rA + (buf) * 16384 + ((pi) * 2 + m2) * 1024 + pc1); \
    } } while (0)

#define MFMA16(pi, abank, bbank) do {                                          \
    _Pragma("unroll") for (int m2 = 0; m2 < 2; ++m2)                           \
    _Pragma("unroll") for (int nj = 0; nj < 4; ++nj) {                         \
      acc[(pi) * 2 + m2][nj] = __builtin_amdgcn_mfma_f32_16x16x32_bf16(        \
          abank[m2][0], bbank[nj][0], acc[(pi) * 2 + m2][nj], 0, 0, 0);        \
      acc[(pi) * 2 + m2][nj] = __builtin_amdgcn_mfma_f32_16x16x32_bf16(        \
          abank[m2][1], bbank[nj][1], acc[(pi) * 2 + m2][nj], 0, 0, 0);        \
    } } while (0)

  // Full iteration (2 K-tiles: buf0 phases 1-4, buf1 phases 5-8).
#define ITER_F() do {                                                          \
    /* ph1 */ SP4(1);           BARRIER(); LOADA(af1, 0, 1);                   \
              PRIO1(); MFMA16(0, af0, bfA); PRIO0();                           \
    /* ph2 */ SP1(0); VMW(10);  BARRIER(); LOADA(af0, 0, 2);                   \
              PRIO1(); MFMA16(1, af1, bfA); PRIO0();                           \
    /* ph3 */ SP2(0);           BARRIER(); LOADA(af1, 0, 3);                   \
              PRIO1(); MFMA16(2, af0, bfA); PRIO0();                           \
    /* ph4 */ SP3(0); VMW(8);   BARRIER(); LOADB(bfB, 1); LOADA(af0, 1, 0);    \
              PRIO1(); MFMA16(3, af1, bfA); PRIO0();                           \
    /* ph5 */ SP4(0);           BARRIER(); LOADA(af1, 1, 1);                   \
              PRIO1(); MFMA16(0, af0, bfB); PRIO0();                           \
    /* ph6 */ SP1(1); VMW(10);  BARRIER(); LOADA(af0, 1, 2);                   \
              PRIO1(); MFMA16(1, af1, bfB); PRIO0();                           \
    /* ph7 */ SP2(1);           BARRIER(); LOADA(af1, 1, 3);                   \
              PRIO1(); MFMA16(2, af0, bfB); PRIO0();                           \
    /* ph8 */ SP3(1); VMW(8);   BARRIER(); LOADB(bfA, 0); LOADA(af0, 0, 0);    \
              PRIO1(); MFMA16(3, af1, bfB); PRIO0();                           \
  } while (0)

  // Tail iteration: no next-iter stages; drains relax 8 -> 2 -> 0.
#define ITER_T() do {                                                          \
    /* ph1 */ SP4(1);           BARRIER(); LOADA(af1, 0, 1);                   \
              PRIO1(); MFMA16(0, af0, bfA); PRIO0();                           \
    /* ph2 */ VMW(8);           BARRIER(); LOADA(af0, 0, 2);                   \
              PRIO1(); MFMA16(1, af1, bfA); PRIO0();                           \
    /* ph3 */                   BARRIER(); LOADA(af1, 0, 3);                   \
              PRIO1(); MFMA16(2, af0, bfA); PRIO0();                           \
    /* ph4 */ VMW(2);           BARRIER(); LOADB(bfB, 1); LOADA(af0, 1, 0);    \
              PRIO1(); MFMA16(3, af1, bfA); PRIO0();                           \
    /* ph5 */                   BARRIER(); LOADA(af1, 1, 1);                   \
              PRIO1(); MFMA16(0, af0, bfB); PRIO0();                           \
    /* ph6 */ VMW(0);           BARRIER(); LOADA(af0, 1, 2);                   \
              PRIO1(); MFMA16(1, af1, bfB); PRIO0();                           \
    /* ph7 */                   BARRIER(); LOADA(af1, 1, 3);                   \
              PRIO1(); MFMA16(2, af0, bfB); PRIO0();                           \
    /* ph8 */                   BARRIER();                                     \
              PRIO1(); MFMA16(3, af1, bfB); PRIO0();                           \
  } while (0)

  // Prologue: stage T0 fully + T1.{B,A-lo} (14 loads); drain T0 (VMW(6)
  // leaves [S4?] -> exactly the steady iter-start pattern of 8 after ph1);
  // barrier publishes staging + wsum; prefetch ph1 fragments.
  SP1(0); SP2(0); SP3(0); SP4(0);   // T0 complete
  SP1(1); SP2(1); SP3(1);           // T1 minus A-hi
  VMW(6);                           // T0 drained; [S1,S2,S3](T1) in flight
  BARRIER();
  LOADB(bfA, 0); LOADA(af0, 0, 0);  // ph1 operands

#pragma unroll 1
  for (int it = 0; it < NITER - 1; ++it) ITER_F();
  ITER_T();

  // Epilogue: C/D layout col = lane&15, row = (lane>>4)*4 + reg
  const float imag = rsqrtf(fmaxf(wsum[0] + wsum[1] + wsum[2] + wsum[3] +
                                  wsum[4] + wsum[5] + wsum[6] + wsum[7], 1e-10f));
#pragma unroll
  for (int mi = 0; mi < 8; ++mi) {
    const int rbase = bm + wr * 128 + mi * 16 + q * 4;
#pragma unroll
    for (int r = 0; r < 4; ++r) {
      const int row = rbase + r;
      const float sc = smag[row] * imag;
      float* crow = C + (size_t)row * N_DIM + bn + wc * 64 + fr;
#pragma unroll
      for (int nj = 0; nj < 4; ++nj) crow[nj * 16] = acc[mi][nj][r] * sc;
    }
  }
}

// ---------------- launch ----------------
extern "C" void kernel_launch(void* const* d_in, const int* in_sizes, int n_in,
                              void* d_out, int out_size, void* d_ws, size_t ws_size,
                              hipStream_t stream) {
  const float* S = (const float*)d_in[0];  // support_set [8192,1024]
  const float* I = (const float*)d_in[1];  // input_image [2048,1024]
  float* out = (float*)d_out;

  // ws layout: Sb bf16 16MB | Ib bf16 4MB | smag 32KB | partials 8KB
  unsigned char* ws = (unsigned char*)d_ws;
  unsigned short* Sb = (unsigned short*)ws;
  unsigned short* Ib = (unsigned short*)(ws + (size_t)M_DIM * K_DIM * 2);
  float* smag = (float*)(ws + (size_t)M_DIM * K_DIM * 2 + (size_t)N_DIM * K_DIM * 2);
  float* partials = smag + M_DIM;

  hipLaunchKernelGGL(prep, dim3(2560), dim3(256), 0, stream,
                     S, I, Sb, Ib, smag, partials);
  hipLaunchKernelGGL(gemm_bt, dim3((M_DIM / BM) * (N_DIM / BN)), dim3(512), 0, stream,
                     Sb, Ib, smag, partials, out);
}